// Round 2
// baseline (425.675 us; speedup 1.0000x reference)
//
#include <hip/hip_runtime.h>

constexpr int Bc = 4, Lc = 1024, Dc = 768, Hc = 12, NEc = 42, Mc = 4, Pc = 512, NLc = 97;
constexpr int BE   = Bc * NEc;   // 168 entities
constexpr int BEp  = 176;        // padded to 11 m-tiles
constexpr int ROWS = Bc * Pc;    // 2048 pairs
constexpr int N2   = 2 * Dc;     // 1536

typedef __attribute__((ext_vector_type(8))) short short8;
typedef _Float16 half8 __attribute__((ext_vector_type(8)));
typedef __attribute__((ext_vector_type(4))) float f32x4;

__device__ __forceinline__ f32x4 mfma_bf(short8 a, short8 b, f32x4 c) {
    return __builtin_amdgcn_mfma_f32_16x16x32_bf16(a, b, c, 0, 0, 0);
}
__device__ __forceinline__ f32x4 mfma_h(half8 a, half8 b, f32x4 c) {
    return __builtin_amdgcn_mfma_f32_16x16x32_f16(a, b, c, 0, 0, 0);
}
__device__ __forceinline__ unsigned short f2bf(float x) {
    unsigned int u = __float_as_uint(x);
    return (unsigned short)((u + 0x7fffu + ((u >> 16) & 1u)) >> 16);
}
__device__ __forceinline__ float bf2f(unsigned short h) {
    return __uint_as_float(((unsigned int)h) << 16);
}
__device__ __forceinline__ short8 ld8(const unsigned short* p) {
    return *(const short8*)(const void*)p;
}
__device__ __forceinline__ half8 ldh8(const _Float16* p) {
    return *(const half8*)(const void*)p;
}

// A/B-pack layout (16x16x32 fragments): idx = ((tile*NKB + kb)*512) + lane*8 + j
// where lane = ((k>>3)&3)*16 + (row_or_col & 15), j = k & 7, kb = k >> 5.

// Fused-prep block ranges
constexpr int PB_EMBS  = 0;                    // 176
constexpr int PB_EATT  = PB_EMBS + BEp;        // +2016 = 2192
constexpr int PB_TRSEQ = PB_EATT + BE * Hc;    // +768  = 2960
constexpr int PB_TRW   = PB_TRSEQ + 768;       // +576  = 3536
constexpr int PB_TRWBI = PB_TRW + 576;         // +768  = 4304
constexpr int PB_ZERO  = PB_TRWBI + 768;       // +97   = 4401
constexpr int PB_TOTAL = PB_ZERO + 97;

// ---------------------------------------------------------------------------
// k_prep: all independent preprocessing in ONE dispatch (branch by block range)
__global__ __launch_bounds__(256) void k_prep(const float* __restrict__ seq,
                                              const float* __restrict__ att,
                                              const int* __restrict__ mpos,
                                              const float* __restrict__ Wh,
                                              const float* __restrict__ Wt,
                                              const float* __restrict__ wbi,
                                              unsigned short* __restrict__ ep,
                                              unsigned short* __restrict__ eatt,
                                              unsigned short* __restrict__ sp,
                                              unsigned short* __restrict__ wp1,
                                              unsigned short* __restrict__ wp2,
                                              _Float16* __restrict__ wbp,
                                              float* __restrict__ out_zero) {
    __shared__ float smem[64 * 97];   // union: 64x65 tiles or 64x97 wbi slab
    int blk = blockIdx.x;
    int t = threadIdx.x;

    if (blk < PB_EATT) {
        // ---- entity logsumexp embeds -> A-pack [11 mt][24 kb] ----
        int be = blk - PB_EMBS, mt = be >> 4, lm = be & 15;
        float vals[3] = {0.f, 0.f, 0.f};
        if (be < BE) {
            int b = be / NEc;
            const int* pp = mpos + be * Mc;
            int p0 = pp[0] + 1, p1 = pp[1] + 1, p2 = pp[2] + 1, p3 = pp[3] + 1;
            const float* s = seq + (size_t)b * Lc * Dc;
            #pragma unroll
            for (int i = 0; i < 3; ++i) {
                int d = t + i * 256;
                float x0 = s[(size_t)p0 * Dc + d], x1 = s[(size_t)p1 * Dc + d];
                float x2 = s[(size_t)p2 * Dc + d], x3 = s[(size_t)p3 * Dc + d];
                float mx = fmaxf(fmaxf(x0, x1), fmaxf(x2, x3));
                vals[i] = mx + logf(expf(x0 - mx) + expf(x1 - mx) + expf(x2 - mx) + expf(x3 - mx));
            }
        }
        #pragma unroll
        for (int i = 0; i < 3; ++i) {
            int d = t + i * 256;
            int idx = ((mt * 24 + (d >> 5)) << 9) + (((d >> 3) & 3) << 7) + (lm << 3) + (d & 7);
            ep[idx] = f2bf(vals[i]);
        }
    } else if (blk < PB_TRSEQ) {
        // ---- entity attention mean -> bf16 [be][h][l] ----
        int idx = blk - PB_EATT;
        int be = idx / Hc, h = idx - be * Hc, b = be / NEc;
        const int* pp = mpos + be * Mc;
        const float* a = att + ((size_t)(b * Hc + h)) * Lc * Lc;
        const float4* r0 = (const float4*)(a + (size_t)(pp[0] + 1) * Lc);
        const float4* r1 = (const float4*)(a + (size_t)(pp[1] + 1) * Lc);
        const float4* r2 = (const float4*)(a + (size_t)(pp[2] + 1) * Lc);
        const float4* r3 = (const float4*)(a + (size_t)(pp[3] + 1) * Lc);
        unsigned short* o = eatt + ((size_t)be * Hc + h) * Lc;
        float4 v0 = r0[t], v1 = r1[t], v2 = r2[t], v3 = r3[t];
        o[t * 4 + 0] = f2bf(0.25f * (v0.x + v1.x + v2.x + v3.x));
        o[t * 4 + 1] = f2bf(0.25f * (v0.y + v1.y + v2.y + v3.y));
        o[t * 4 + 2] = f2bf(0.25f * (v0.z + v1.z + v2.z + v3.z));
        o[t * 4 + 3] = f2bf(0.25f * (v0.w + v1.w + v2.w + v3.w));
    } else if (blk < PB_TRW) {
        // ---- seq [B,L,D] f32 -> B-pack [b][48 nt][32 kb] bf16 (n=d, k=l) ----
        int idx = blk - PB_TRSEQ;
        int xb = idx & 15, yb = (idx >> 4) % 12, b = idx / 192;
        int l0 = xb * 64, d0 = yb * 64;
        const float* s = seq + (size_t)b * Lc * Dc;
        #pragma unroll
        for (int i = 0; i < 16; ++i) {
            int ii = t + i * 256, r = ii >> 6, c = ii & 63;
            smem[r * 65 + c] = s[(size_t)(l0 + r) * Dc + d0 + c];
        }
        __syncthreads();
        unsigned short* outb = sp + (size_t)b * 48 * 32 * 512;
        int flat = t * 2, lane = flat >> 3, j = flat & 7;
        #pragma unroll
        for (int nt_i = 0; nt_i < 4; ++nt_i)
            #pragma unroll
            for (int kb_i = 0; kb_i < 2; ++kb_i) {
                int kl = kb_i * 32 + (lane >> 4) * 8 + j;
                int c  = nt_i * 16 + (lane & 15);
                unsigned int v = (unsigned)f2bf(smem[kl * 65 + c]) |
                                 ((unsigned)f2bf(smem[(kl + 1) * 65 + c]) << 16);
                *(unsigned int*)&outb[(((d0 / 16 + nt_i) * 32 + (l0 / 32 + kb_i)) << 9) + flat] = v;
            }
    } else if (blk < PB_TRWBI) {
        // ---- Wh/Wt [1536][768] -> B-pack wp1/wp2 [96 nt][24 kb] ----
        int idx = blk - PB_TRW;
        int xb = idx % 24, yb = (idx / 24) % 12, which = idx / 288;
        int k0 = xb * 64, n0 = yb * 64;
        const float* W = which ? Wt : Wh;
        #pragma unroll
        for (int i = 0; i < 16; ++i) {
            int ii = t + i * 256, r = ii >> 6, c = ii & 63;
            smem[r * 65 + c] = W[(size_t)(k0 + r) * Dc + n0 + c];
        }
        __syncthreads();
        unsigned short* dst = (k0 < Dc) ? wp1 : wp2;
        int kb0 = ((k0 < Dc) ? k0 : (k0 - Dc)) / 32;
        int nt0 = which * 48 + n0 / 16;
        int flat = t * 2, lane = flat >> 3, j = flat & 7;
        #pragma unroll
        for (int nt_i = 0; nt_i < 4; ++nt_i)
            #pragma unroll
            for (int kb_i = 0; kb_i < 2; ++kb_i) {
                int kl = kb_i * 32 + (lane >> 4) * 8 + j;
                int c  = nt_i * 16 + (lane & 15);
                unsigned int v = (unsigned)f2bf(smem[kl * 65 + c]) |
                                 ((unsigned)f2bf(smem[(kl + 1) * 65 + c]) << 16);
                *(unsigned int*)&dst[(((nt0 + nt_i) * 24 + kb0 + kb_i) << 9) + flat] = v;
            }
    } else if (blk < PB_ZERO) {
        // ---- W_bi [49152,97] f32 -> f16 B-pack [(nt*12+g)*64+x][2 half][512] ----
        int idx = blk - PB_TRWBI;
        int x = idx & 63, g = idx >> 6;
        const float* src = wbi + (size_t)(g * 4096 + x * 64) * NLc;
        for (int i = t; i < 64 * NLc; i += 256) smem[i] = src[i];
        __syncthreads();
        int flat = t * 2, lane = flat >> 3, j = flat & 7;
        int lm = lane & 15, qj = (lane >> 4) * 8 + j;
        #pragma unroll
        for (int nt = 0; nt < 7; ++nt)
            #pragma unroll
            for (int half = 0; half < 2; ++half) {
                int y = half * 32 + qj;
                int n = nt * 16 + lm;
                _Float16 v0 = (n < NLc) ? (_Float16)smem[y * NLc + n] : (_Float16)0.f;
                _Float16 v1 = (n < NLc) ? (_Float16)smem[(y + 1) * NLc + n] : (_Float16)0.f;
                size_t base = ((((size_t)(nt * 12 + g) * 64 + x) * 2 + half) << 9);
                _Float16* d = wbp + base + flat;
                d[0] = v0; d[1] = v1;
            }
    } else {
        // ---- zero d_out (2048*97 f32 = 97 blocks x 2048 floats) ----
        int idx = blk - PB_ZERO;
        float4* o = (float4*)(out_zero + (size_t)idx * 2048);
        float4 z = {0.f, 0.f, 0.f, 0.f};
        o[t] = z;
        o[t + 256] = z;
    }
}

// ---------------------------------------------------------------------------
// pair weights -> A-pack [128 mt][32 kb]
__global__ __launch_bounds__(256) void k_pairw(const unsigned short* __restrict__ eatt,
                                               const int* __restrict__ hts,
                                               unsigned short* __restrict__ pwp) {
    int bp = blockIdx.x, b = bp / Pc;
    int hi = hts[bp * 2], ti = hts[bp * 2 + 1];
    const unsigned short* ai = eatt + ((size_t)(b * NEc + hi)) * Hc * Lc;
    const unsigned short* aj = eatt + ((size_t)(b * NEc + ti)) * Hc * Lc;
    int l0 = threadIdx.x * 4;
    float acc[4] = {0.f, 0.f, 0.f, 0.f};
    #pragma unroll
    for (int h = 0; h < Hc; ++h) {
        uint2 ua = *(const uint2*)(ai + h * Lc + l0);
        uint2 ub = *(const uint2*)(aj + h * Lc + l0);
        acc[0] += bf2f(ua.x & 0xffff) * bf2f(ub.x & 0xffff);
        acc[1] += bf2f(ua.x >> 16)    * bf2f(ub.x >> 16);
        acc[2] += bf2f(ua.y & 0xffff) * bf2f(ub.y & 0xffff);
        acc[3] += bf2f(ua.y >> 16)    * bf2f(ub.y >> 16);
    }
    float lsum = acc[0] + acc[1] + acc[2] + acc[3];
    #pragma unroll
    for (int off = 32; off > 0; off >>= 1) lsum += __shfl_down(lsum, off, 64);
    __shared__ float red[4];
    __shared__ float sinv;
    int lane = threadIdx.x & 63, wv = threadIdx.x >> 6;
    if (lane == 0) red[wv] = lsum;
    __syncthreads();
    if (threadIdx.x == 0) sinv = 1.f / (red[0] + red[1] + red[2] + red[3] + 1.2e-4f);
    __syncthreads();
    float s = sinv;
    unsigned short w0 = f2bf(acc[0] * s), w1 = f2bf(acc[1] * s);
    unsigned short w2 = f2bf(acc[2] * s), w3 = f2bf(acc[3] * s);
    int mt = bp >> 4, lm = bp & 15, kb = l0 >> 5, quad = (l0 >> 3) & 3, j0 = l0 & 7;
    unsigned short* dst = pwp + ((mt * 32 + kb) << 9) + (quad << 7) + (lm << 3) + j0;
    *(uint2*)dst = make_uint2((unsigned)w0 | ((unsigned)w1 << 16),
                              (unsigned)w2 | ((unsigned)w3 << 16));
}

// ---------------------------------------------------------------------------
// fused: k_rs (blocks 0..383) + k_E (blocks 384..647)
__global__ __launch_bounds__(256) void k_rsE(const unsigned short* __restrict__ pwp,
                                             const unsigned short* __restrict__ sp,
                                             const unsigned short* __restrict__ ep,
                                             const unsigned short* __restrict__ wp1,
                                             unsigned short* __restrict__ rsp,
                                             unsigned short* __restrict__ E) {
    int tid = threadIdx.x, wave = tid >> 6, lane = tid & 63;
    int quad = lane >> 4, lm = lane & 15;
    int blk = blockIdx.x;
    if (blk < 384) {
        // rs = pw @ seq -> A-pack [128 mt][24 kb]
        int mb = blk & 7, ntq = (blk >> 3) % 12, b = blk / 96;
        int nt = ntq * 4 + wave;
        int mt0 = b * 32 + mb * 4;
        const unsigned short* bbase = sp + (((size_t)b * 48 + nt) * 32 << 9) + lane * 8;
        const unsigned short* abase = pwp + ((size_t)mt0 * 32 << 9) + lane * 8;
        f32x4 acc[4] = {};
        for (int kb = 0; kb < 32; ++kb) {
            short8 bf = ld8(bbase + kb * 512);
            #pragma unroll
            for (int mf = 0; mf < 4; ++mf)
                acc[mf] = mfma_bf(ld8(abase + (mf * 32 + kb) * 512), bf, acc[mf]);
        }
        int n = nt * 16 + lm, kbo = n >> 5, lq = ((n >> 3) & 3) << 4, jo = n & 7;
        #pragma unroll
        for (int mf = 0; mf < 4; ++mf) {
            unsigned short* db = rsp + (((mt0 + mf) * 24 + kbo) << 9) + jo;
            #pragma unroll
            for (int r = 0; r < 4; ++r)
                db[(lq + quad * 4 + r) << 3] = f2bf(acc[mf][r]);
        }
    } else {
        // E[be][n'] = emb[be] @ [Wh1 | Wt1] -> bf16 [176][1536]
        int idx = blk - 384;
        int mt = idx % 11, ntq = idx / 11;
        int nt = ntq * 4 + wave;
        const unsigned short* ab = ep + (mt * 24 << 9) + lane * 8;
        const unsigned short* bb = wp1 + (nt * 24 << 9) + lane * 8;
        f32x4 acc = {};
        for (int kb = 0; kb < 24; ++kb)
            acc = mfma_bf(ld8(ab + kb * 512), ld8(bb + kb * 512), acc);
        #pragma unroll
        for (int r = 0; r < 4; ++r)
            E[(size_t)(mt * 16 + quad * 4 + r) * N2 + nt * 16 + lm] = f2bf(acc[r]);
    }
}

// ---------------------------------------------------------------------------
// R = rs @ [Wh2 | Wt2] fused with zfin epilogue:
//   zs = tanh(E_h + R_left + bh)  -> f16 row-major [2048][768]
//   zo = tanh(E_t + R_right + bt) -> f16 A-pack
// grid (32 mb, 24 ntq); acc stays in f32 registers (no R round-trip).
__global__ __launch_bounds__(256) void k_Rz(const unsigned short* __restrict__ rsp,
                                            const unsigned short* __restrict__ wp2,
                                            const unsigned short* __restrict__ E,
                                            const int* __restrict__ hts,
                                            const float* __restrict__ bh,
                                            const float* __restrict__ bt,
                                            _Float16* __restrict__ zs,
                                            _Float16* __restrict__ zop) {
    int tid = threadIdx.x, wave = tid >> 6, lane = tid & 63;
    int quad = lane >> 4, lm = lane & 15;
    int mt0 = blockIdx.x * 4, nt = blockIdx.y * 4 + wave;
    const unsigned short* bb = wp2 + (nt * 24 << 9) + lane * 8;
    const unsigned short* ab = rsp + ((size_t)mt0 * 24 << 9) + lane * 8;
    f32x4 acc[4] = {};
    for (int kb = 0; kb < 24; ++kb) {
        short8 bf = ld8(bb + kb * 512);
        #pragma unroll
        for (int mf = 0; mf < 4; ++mf)
            acc[mf] = mfma_bf(ld8(ab + (mf * 24 + kb) * 512), bf, acc[mf]);
    }
    // epilogue: fused zfin. np-band is wave-uniform: nt<48 -> zs half, else zo half.
    int np = nt * 16 + lm;             // n' in [0,1536)
    bool is_zs = (np < Dc);
    int n = is_zs ? np : np - Dc;
    float bias = is_zs ? bh[n] : bt[n];
    #pragma unroll
    for (int mf = 0; mf < 4; ++mf) {
        int rowbase = (mt0 + mf) * 16 + quad * 4;
        #pragma unroll
        for (int r = 0; r < 4; ++r) {
            int row = rowbase + r;
            int b = row >> 9;
            int hh = hts[row * 2], tt = hts[row * 2 + 1];
            int ent = is_zs ? hh : tt;
            float ev = bf2f(E[(size_t)(b * NEc + ent) * N2 + np]);
            float v = tanhf(ev + acc[mf][r] + bias);
            if (is_zs) {
                zs[(size_t)row * Dc + n] = (_Float16)v;
            } else {
                int idx = (((row >> 4) * 24 + (n >> 5)) << 9) +
                          (((((n >> 3) & 3) << 4) + (row & 15)) << 3) + (n & 7);
                zop[idx] = (_Float16)v;
            }
        }
    }
}

// ---------------------------------------------------------------------------
// grouped bilinear: out[row,n] += sum_{x,y} zs[row,gx] zo[row,gy] W[g,x,y,n]
// grid (8 pb, 12 g, 4 z), z = mfh + 2*xh.  Each wave: 2 m-tiles (32 rows),
// ALL 7 nt bands, half the x range.  A-fragments (zs-scaled zo) built once per
// x and reused across 7 nt bands (28 MFMA per x vs 8 before) -> MFMA-bound.
__global__ __launch_bounds__(256) void k_bilin(const _Float16* __restrict__ zs,
                                               const _Float16* __restrict__ zop,
                                               const _Float16* __restrict__ wbp,
                                               const float* __restrict__ bbi,
                                               float* __restrict__ out) {
    __shared__ _Float16 zlds[256 * 72];
    int tid = threadIdx.x, wave = tid >> 6, lane = tid & 63;
    int quad = lane >> 4, lm = lane & 15;
    int pb = blockIdx.x, g = blockIdx.y, z = blockIdx.z;
    int mfh = z & 1, xh = z >> 1;
    {
        const half8* src = (const half8*)(zs + ((size_t)(pb * 256 + tid)) * Dc + g * 64);
        half8* dst = (half8*)&zlds[tid * 72];
        #pragma unroll
        for (int c = 0; c < 8; ++c) dst[c] = src[c];   // 64 halves = full group slice
    }
    __syncthreads();
    int mt0 = pb * 16 + wave * 4 + mfh * 2;            // two m-tiles: mt0, mt0+1
    half8 zofr0[2], zofr1[2];
    #pragma unroll
    for (int hf = 0; hf < 2; ++hf) {
        zofr0[hf] = ldh8(zop + (((mt0 + 0) * 24 + g * 2 + hf) << 9) + lane * 8);
        zofr1[hf] = ldh8(zop + (((mt0 + 1) * 24 + g * 2 + hf) << 9) + lane * 8);
    }
    const _Float16* wg = wbp + ((size_t)g << 16) + lane * 8;
    const _Float16* zrow = &zlds[(size_t)(wave * 64 + mfh * 32 + lm) * 72];
    f32x4 acc0[7] = {};
    f32x4 acc1[7] = {};
    for (int xi = 0; xi < 32; ++xi) {
        int x = xh * 32 + xi;
        _Float16 s0 = zrow[x];
        _Float16 s1 = zrow[16 * 72 + x];
        half8 bc0 = {s0, s0, s0, s0, s0, s0, s0, s0};
        half8 bc1 = {s1, s1, s1, s1, s1, s1, s1, s1};
        half8 a00 = bc0 * zofr0[0];
        half8 a01 = bc0 * zofr0[1];
        half8 a10 = bc1 * zofr1[0];
        half8 a11 = bc1 * zofr1[1];
        const _Float16* wx = wg + (size_t)x * 1024;
        #pragma unroll
        for (int nt = 0; nt < 7; ++nt) {
            const _Float16* p = wx + ((size_t)(nt * 12) << 16);
            half8 b0 = ldh8(p);
            half8 b1 = ldh8(p + 512);
            acc0[nt] = mfma_h(a00, b0, acc0[nt]);
            acc0[nt] = mfma_h(a01, b1, acc0[nt]);
            acc1[nt] = mfma_h(a10, b0, acc1[nt]);
            acc1[nt] = mfma_h(a11, b1, acc1[nt]);
        }
    }
    #pragma unroll
    for (int nt = 0; nt < 7; ++nt) {
        int n = nt * 16 + lm;
        if (n < NLc) {
            float bias = (g == 0 && xh == 0) ? bbi[n] : 0.f;
            #pragma unroll
            for (int r = 0; r < 4; ++r) {
                int row0 = (mt0 + 0) * 16 + quad * 4 + r;
                int row1 = (mt0 + 1) * 16 + quad * 4 + r;
                atomicAdd(out + (size_t)row0 * NLc + n, acc0[nt][r] + bias);
                atomicAdd(out + (size_t)row1 * NLc + n, acc1[nt][r] + bias);
            }
        }
    }
}

// ---------------------------------------------------------------------------
extern "C" void kernel_launch(void* const* d_in, const int* in_sizes, int n_in,
                              void* d_out, int out_size, void* d_ws, size_t ws_size,
                              hipStream_t stream) {
    const float* seq  = (const float*)d_in[0];
    const float* att  = (const float*)d_in[1];
    const int*   mpos = (const int*)d_in[2];
    const int*   hts  = (const int*)d_in[3];
    const float* Wh   = (const float*)d_in[4];
    const float* bh   = (const float*)d_in[5];
    const float* Wt   = (const float*)d_in[6];
    const float* bt   = (const float*)d_in[7];
    const float* Wbi  = (const float*)d_in[8];
    const float* bbi  = (const float*)d_in[9];
    float* out = (float*)d_out;

    // Workspace layout
    char* w = (char*)d_ws;
    unsigned short* embs_p = (unsigned short*)(w);                 //   270,336
    unsigned short* eatt_b = (unsigned short*)(w + 270336);        // 4,128,768
    unsigned short* pw_p   = (unsigned short*)(w + 4399104);       // 4,194,304
    unsigned short* seq_p  = (unsigned short*)(w + 8593408);       // 6,291,456
    _Float16*       wbi_p  = (_Float16*)(w + 14884864);            // 11,010,048
    unsigned short* wp1    = (unsigned short*)(w + 25894912);      // 2,359,296
    unsigned short* wp2    = (unsigned short*)(w + 28254208);      // 2,359,296
    unsigned short* E      = (unsigned short*)(w + 30613504);      //   540,672
    unsigned short* rs_p   = (unsigned short*)(w + 31154176);      // 3,145,728
    _Float16*       zs     = (_Float16*)(w + 34299904);            // 3,145,728
    _Float16*       zo_p   = (_Float16*)(w + 37445632);            // 3,145,728
    // total 40,591,360 B

    k_prep <<<PB_TOTAL, 256, 0, stream>>>(seq, att, mpos, Wh, Wt, Wbi,
                                          embs_p, eatt_b, seq_p, wp1, wp2, wbi_p, out);
    k_pairw<<<ROWS, 256, 0, stream>>>(eatt_b, hts, pw_p);
    k_rsE  <<<648, 256, 0, stream>>>(pw_p, seq_p, embs_p, wp1, rs_p, E);
    k_Rz   <<<dim3(32, 24), 256, 0, stream>>>(rs_p, wp2, E, hts, bh, bt, zs, zo_p);
    k_bilin<<<dim3(8, 12, 4), 256, 0, stream>>>(zs, zo_p, wbi_p, bbi, out);
}

// Round 3
// 372.214 us; speedup vs baseline: 1.1436x; 1.1436x over previous
//
#include <hip/hip_runtime.h>

constexpr int Bc = 4, Lc = 1024, Dc = 768, Hc = 12, NEc = 42, Mc = 4, Pc = 512, NLc = 97;
constexpr int BE   = Bc * NEc;   // 168 entities
constexpr int BEp  = 176;        // padded to 11 m-tiles
constexpr int ROWS = Bc * Pc;    // 2048 pairs
constexpr int N2   = 2 * Dc;     // 1536

typedef __attribute__((ext_vector_type(8))) short short8;
typedef _Float16 half8 __attribute__((ext_vector_type(8)));
typedef __attribute__((ext_vector_type(4))) float f32x4;

__device__ __forceinline__ f32x4 mfma_bf(short8 a, short8 b, f32x4 c) {
    return __builtin_amdgcn_mfma_f32_16x16x32_bf16(a, b, c, 0, 0, 0);
}
__device__ __forceinline__ f32x4 mfma_h(half8 a, half8 b, f32x4 c) {
    return __builtin_amdgcn_mfma_f32_16x16x32_f16(a, b, c, 0, 0, 0);
}
__device__ __forceinline__ unsigned short f2bf(float x) {
    unsigned int u = __float_as_uint(x);
    return (unsigned short)((u + 0x7fffu + ((u >> 16) & 1u)) >> 16);
}
__device__ __forceinline__ float bf2f(unsigned short h) {
    return __uint_as_float(((unsigned int)h) << 16);
}
__device__ __forceinline__ short8 ld8(const unsigned short* p) {
    return *(const short8*)(const void*)p;
}
__device__ __forceinline__ half8 ldh8(const _Float16* p) {
    return *(const half8*)(const void*)p;
}
// fast tanh: 1 - 2/(e^{2x}+1), clamped so exp never overflows.
// ~6 VALU ops vs ~25-40 for libm tanhf; |err| ~1e-6 (irrelevant vs bf16 noise).
__device__ __forceinline__ float fast_tanh(float x) {
    float cx = fminf(fmaxf(x, -9.f), 9.f);
    float u = __expf(2.f * cx);
    return 1.f - 2.f / (u + 1.f);
}

// A/B-pack layout (16x16x32 fragments): idx = ((tile*NKB + kb)*512) + lane*8 + j
// where lane = ((k>>3)&3)*16 + (row_or_col & 15), j = k & 7, kb = k >> 5.

// Fused-prep block ranges
constexpr int PB_EMBS  = 0;                    // 176
constexpr int PB_EATT  = PB_EMBS + BEp;        // +2016 = 2192
constexpr int PB_TRSEQ = PB_EATT + BE * Hc;    // +768  = 2960
constexpr int PB_TRW   = PB_TRSEQ + 768;       // +576  = 3536
constexpr int PB_TRWBI = PB_TRW + 576;         // +768  = 4304
constexpr int PB_ZERO  = PB_TRWBI + 768;       // +97   = 4401
constexpr int PB_TOTAL = PB_ZERO + 97;

// ---------------------------------------------------------------------------
// k_prep: all independent preprocessing in ONE dispatch (branch by block range)
__global__ __launch_bounds__(256) void k_prep(const float* __restrict__ seq,
                                              const float* __restrict__ att,
                                              const int* __restrict__ mpos,
                                              const float* __restrict__ Wh,
                                              const float* __restrict__ Wt,
                                              const float* __restrict__ wbi,
                                              unsigned short* __restrict__ ep,
                                              unsigned short* __restrict__ eatt,
                                              unsigned short* __restrict__ sp,
                                              unsigned short* __restrict__ wp1,
                                              unsigned short* __restrict__ wp2,
                                              _Float16* __restrict__ wbp,
                                              float* __restrict__ out_zero) {
    __shared__ float smem[64 * 97];   // union: 64x65 tiles or 64x97 wbi slab
    int blk = blockIdx.x;
    int t = threadIdx.x;

    if (blk < PB_EATT) {
        // ---- entity logsumexp embeds -> A-pack [11 mt][24 kb] ----
        int be = blk - PB_EMBS, mt = be >> 4, lm = be & 15;
        float vals[3] = {0.f, 0.f, 0.f};
        if (be < BE) {
            int b = be / NEc;
            const int* pp = mpos + be * Mc;
            int p0 = pp[0] + 1, p1 = pp[1] + 1, p2 = pp[2] + 1, p3 = pp[3] + 1;
            const float* s = seq + (size_t)b * Lc * Dc;
            #pragma unroll
            for (int i = 0; i < 3; ++i) {
                int d = t + i * 256;
                float x0 = s[(size_t)p0 * Dc + d], x1 = s[(size_t)p1 * Dc + d];
                float x2 = s[(size_t)p2 * Dc + d], x3 = s[(size_t)p3 * Dc + d];
                float mx = fmaxf(fmaxf(x0, x1), fmaxf(x2, x3));
                vals[i] = mx + logf(expf(x0 - mx) + expf(x1 - mx) + expf(x2 - mx) + expf(x3 - mx));
            }
        }
        #pragma unroll
        for (int i = 0; i < 3; ++i) {
            int d = t + i * 256;
            int idx = ((mt * 24 + (d >> 5)) << 9) + (((d >> 3) & 3) << 7) + (lm << 3) + (d & 7);
            ep[idx] = f2bf(vals[i]);
        }
    } else if (blk < PB_TRSEQ) {
        // ---- entity attention mean -> bf16 [be][h][l] ----
        int idx = blk - PB_EATT;
        int be = idx / Hc, h = idx - be * Hc, b = be / NEc;
        const int* pp = mpos + be * Mc;
        const float* a = att + ((size_t)(b * Hc + h)) * Lc * Lc;
        const float4* r0 = (const float4*)(a + (size_t)(pp[0] + 1) * Lc);
        const float4* r1 = (const float4*)(a + (size_t)(pp[1] + 1) * Lc);
        const float4* r2 = (const float4*)(a + (size_t)(pp[2] + 1) * Lc);
        const float4* r3 = (const float4*)(a + (size_t)(pp[3] + 1) * Lc);
        unsigned short* o = eatt + ((size_t)be * Hc + h) * Lc;
        float4 v0 = r0[t], v1 = r1[t], v2 = r2[t], v3 = r3[t];
        o[t * 4 + 0] = f2bf(0.25f * (v0.x + v1.x + v2.x + v3.x));
        o[t * 4 + 1] = f2bf(0.25f * (v0.y + v1.y + v2.y + v3.y));
        o[t * 4 + 2] = f2bf(0.25f * (v0.z + v1.z + v2.z + v3.z));
        o[t * 4 + 3] = f2bf(0.25f * (v0.w + v1.w + v2.w + v3.w));
    } else if (blk < PB_TRW) {
        // ---- seq [B,L,D] f32 -> B-pack [b][48 nt][32 kb] bf16 (n=d, k=l) ----
        int idx = blk - PB_TRSEQ;
        int xb = idx & 15, yb = (idx >> 4) % 12, b = idx / 192;
        int l0 = xb * 64, d0 = yb * 64;
        const float* s = seq + (size_t)b * Lc * Dc;
        #pragma unroll
        for (int i = 0; i < 16; ++i) {
            int ii = t + i * 256, r = ii >> 6, c = ii & 63;
            smem[r * 65 + c] = s[(size_t)(l0 + r) * Dc + d0 + c];
        }
        __syncthreads();
        unsigned short* outb = sp + (size_t)b * 48 * 32 * 512;
        int flat = t * 2, lane = flat >> 3, j = flat & 7;
        #pragma unroll
        for (int nt_i = 0; nt_i < 4; ++nt_i)
            #pragma unroll
            for (int kb_i = 0; kb_i < 2; ++kb_i) {
                int kl = kb_i * 32 + (lane >> 4) * 8 + j;
                int c  = nt_i * 16 + (lane & 15);
                unsigned int v = (unsigned)f2bf(smem[kl * 65 + c]) |
                                 ((unsigned)f2bf(smem[(kl + 1) * 65 + c]) << 16);
                *(unsigned int*)&outb[(((d0 / 16 + nt_i) * 32 + (l0 / 32 + kb_i)) << 9) + flat] = v;
            }
    } else if (blk < PB_TRWBI) {
        // ---- Wh/Wt [1536][768] -> B-pack wp1/wp2 [96 nt][24 kb] ----
        int idx = blk - PB_TRW;
        int xb = idx % 24, yb = (idx / 24) % 12, which = idx / 288;
        int k0 = xb * 64, n0 = yb * 64;
        const float* W = which ? Wt : Wh;
        #pragma unroll
        for (int i = 0; i < 16; ++i) {
            int ii = t + i * 256, r = ii >> 6, c = ii & 63;
            smem[r * 65 + c] = W[(size_t)(k0 + r) * Dc + n0 + c];
        }
        __syncthreads();
        unsigned short* dst = (k0 < Dc) ? wp1 : wp2;
        int kb0 = ((k0 < Dc) ? k0 : (k0 - Dc)) / 32;
        int nt0 = which * 48 + n0 / 16;
        int flat = t * 2, lane = flat >> 3, j = flat & 7;
        #pragma unroll
        for (int nt_i = 0; nt_i < 4; ++nt_i)
            #pragma unroll
            for (int kb_i = 0; kb_i < 2; ++kb_i) {
                int kl = kb_i * 32 + (lane >> 4) * 8 + j;
                int c  = nt_i * 16 + (lane & 15);
                unsigned int v = (unsigned)f2bf(smem[kl * 65 + c]) |
                                 ((unsigned)f2bf(smem[(kl + 1) * 65 + c]) << 16);
                *(unsigned int*)&dst[(((nt0 + nt_i) * 24 + kb0 + kb_i) << 9) + flat] = v;
            }
    } else if (blk < PB_ZERO) {
        // ---- W_bi [49152,97] f32 -> f16 B-pack [(nt*12+g)*64+x][2 half][512] ----
        int idx = blk - PB_TRWBI;
        int x = idx & 63, g = idx >> 6;
        const float* src = wbi + (size_t)(g * 4096 + x * 64) * NLc;
        for (int i = t; i < 64 * NLc; i += 256) smem[i] = src[i];
        __syncthreads();
        int flat = t * 2, lane = flat >> 3, j = flat & 7;
        int lm = lane & 15, qj = (lane >> 4) * 8 + j;
        #pragma unroll
        for (int nt = 0; nt < 7; ++nt)
            #pragma unroll
            for (int half = 0; half < 2; ++half) {
                int y = half * 32 + qj;
                int n = nt * 16 + lm;
                _Float16 v0 = (n < NLc) ? (_Float16)smem[y * NLc + n] : (_Float16)0.f;
                _Float16 v1 = (n < NLc) ? (_Float16)smem[(y + 1) * NLc + n] : (_Float16)0.f;
                size_t base = ((((size_t)(nt * 12 + g) * 64 + x) * 2 + half) << 9);
                _Float16* d = wbp + base + flat;
                d[0] = v0; d[1] = v1;
            }
    } else {
        // ---- zero d_out (2048*97 f32 = 97 blocks x 2048 floats) ----
        int idx = blk - PB_ZERO;
        float4* o = (float4*)(out_zero + (size_t)idx * 2048);
        float4 z = {0.f, 0.f, 0.f, 0.f};
        o[t] = z;
        o[t + 256] = z;
    }
}

// ---------------------------------------------------------------------------
// pair weights -> A-pack [128 mt][32 kb]
__global__ __launch_bounds__(256) void k_pairw(const unsigned short* __restrict__ eatt,
                                               const int* __restrict__ hts,
                                               unsigned short* __restrict__ pwp) {
    int bp = blockIdx.x, b = bp / Pc;
    int hi = hts[bp * 2], ti = hts[bp * 2 + 1];
    const unsigned short* ai = eatt + ((size_t)(b * NEc + hi)) * Hc * Lc;
    const unsigned short* aj = eatt + ((size_t)(b * NEc + ti)) * Hc * Lc;
    int l0 = threadIdx.x * 4;
    float acc[4] = {0.f, 0.f, 0.f, 0.f};
    #pragma unroll
    for (int h = 0; h < Hc; ++h) {
        uint2 ua = *(const uint2*)(ai + h * Lc + l0);
        uint2 ub = *(const uint2*)(aj + h * Lc + l0);
        acc[0] += bf2f(ua.x & 0xffff) * bf2f(ub.x & 0xffff);
        acc[1] += bf2f(ua.x >> 16)    * bf2f(ub.x >> 16);
        acc[2] += bf2f(ua.y & 0xffff) * bf2f(ub.y & 0xffff);
        acc[3] += bf2f(ua.y >> 16)    * bf2f(ub.y >> 16);
    }
    float lsum = acc[0] + acc[1] + acc[2] + acc[3];
    #pragma unroll
    for (int off = 32; off > 0; off >>= 1) lsum += __shfl_down(lsum, off, 64);
    __shared__ float red[4];
    __shared__ float sinv;
    int lane = threadIdx.x & 63, wv = threadIdx.x >> 6;
    if (lane == 0) red[wv] = lsum;
    __syncthreads();
    if (threadIdx.x == 0) sinv = 1.f / (red[0] + red[1] + red[2] + red[3] + 1.2e-4f);
    __syncthreads();
    float s = sinv;
    unsigned short w0 = f2bf(acc[0] * s), w1 = f2bf(acc[1] * s);
    unsigned short w2 = f2bf(acc[2] * s), w3 = f2bf(acc[3] * s);
    int mt = bp >> 4, lm = bp & 15, kb = l0 >> 5, quad = (l0 >> 3) & 3, j0 = l0 & 7;
    unsigned short* dst = pwp + ((mt * 32 + kb) << 9) + (quad << 7) + (lm << 3) + j0;
    *(uint2*)dst = make_uint2((unsigned)w0 | ((unsigned)w1 << 16),
                              (unsigned)w2 | ((unsigned)w3 << 16));
}

// ---------------------------------------------------------------------------
// fused: k_rs (blocks 0..383) + k_E (blocks 384..647)
__global__ __launch_bounds__(256) void k_rsE(const unsigned short* __restrict__ pwp,
                                             const unsigned short* __restrict__ sp,
                                             const unsigned short* __restrict__ ep,
                                             const unsigned short* __restrict__ wp1,
                                             unsigned short* __restrict__ rsp,
                                             unsigned short* __restrict__ E) {
    int tid = threadIdx.x, wave = tid >> 6, lane = tid & 63;
    int quad = lane >> 4, lm = lane & 15;
    int blk = blockIdx.x;
    if (blk < 384) {
        // rs = pw @ seq -> A-pack [128 mt][24 kb]
        int mb = blk & 7, ntq = (blk >> 3) % 12, b = blk / 96;
        int nt = ntq * 4 + wave;
        int mt0 = b * 32 + mb * 4;
        const unsigned short* bbase = sp + (((size_t)b * 48 + nt) * 32 << 9) + lane * 8;
        const unsigned short* abase = pwp + ((size_t)mt0 * 32 << 9) + lane * 8;
        f32x4 acc[4] = {};
        for (int kb = 0; kb < 32; ++kb) {
            short8 bf = ld8(bbase + kb * 512);
            #pragma unroll
            for (int mf = 0; mf < 4; ++mf)
                acc[mf] = mfma_bf(ld8(abase + (mf * 32 + kb) * 512), bf, acc[mf]);
        }
        int n = nt * 16 + lm, kbo = n >> 5, lq = ((n >> 3) & 3) << 4, jo = n & 7;
        #pragma unroll
        for (int mf = 0; mf < 4; ++mf) {
            unsigned short* db = rsp + (((mt0 + mf) * 24 + kbo) << 9) + jo;
            #pragma unroll
            for (int r = 0; r < 4; ++r)
                db[(lq + quad * 4 + r) << 3] = f2bf(acc[mf][r]);
        }
    } else {
        // E[be][n'] = emb[be] @ [Wh1 | Wt1] -> bf16 [176][1536]
        int idx = blk - 384;
        int mt = idx % 11, ntq = idx / 11;
        int nt = ntq * 4 + wave;
        const unsigned short* ab = ep + (mt * 24 << 9) + lane * 8;
        const unsigned short* bb = wp1 + (nt * 24 << 9) + lane * 8;
        f32x4 acc = {};
        for (int kb = 0; kb < 24; ++kb)
            acc = mfma_bf(ld8(ab + kb * 512), ld8(bb + kb * 512), acc);
        #pragma unroll
        for (int r = 0; r < 4; ++r)
            E[(size_t)(mt * 16 + quad * 4 + r) * N2 + nt * 16 + lm] = f2bf(acc[r]);
    }
}

// ---------------------------------------------------------------------------
// R = rs @ [Wh2 | Wt2] fused with zfin epilogue:
//   zs = tanh(E_h + R_left + bh)  -> f16 row-major [2048][768]
//   zo = tanh(E_t + R_right + bt) -> f16 A-pack
// grid (32 mb, 24 ntq); acc stays in f32 registers (no R round-trip).
__global__ __launch_bounds__(256) void k_Rz(const unsigned short* __restrict__ rsp,
                                            const unsigned short* __restrict__ wp2,
                                            const unsigned short* __restrict__ E,
                                            const int* __restrict__ hts,
                                            const float* __restrict__ bh,
                                            const float* __restrict__ bt,
                                            _Float16* __restrict__ zs,
                                            _Float16* __restrict__ zop) {
    int tid = threadIdx.x, wave = tid >> 6, lane = tid & 63;
    int quad = lane >> 4, lm = lane & 15;
    int mt0 = blockIdx.x * 4, nt = blockIdx.y * 4 + wave;
    const unsigned short* bb = wp2 + (nt * 24 << 9) + lane * 8;
    const unsigned short* ab = rsp + ((size_t)mt0 * 24 << 9) + lane * 8;
    f32x4 acc[4] = {};
    for (int kb = 0; kb < 24; ++kb) {
        short8 bf = ld8(bb + kb * 512);
        #pragma unroll
        for (int mf = 0; mf < 4; ++mf)
            acc[mf] = mfma_bf(ld8(ab + (mf * 24 + kb) * 512), bf, acc[mf]);
    }
    // epilogue: fused zfin. np-band is wave-uniform: nt<48 -> zs half, else zo half.
    int np = nt * 16 + lm;             // n' in [0,1536)
    bool is_zs = (np < Dc);
    int n = is_zs ? np : np - Dc;
    float bias = is_zs ? bh[n] : bt[n];
    #pragma unroll
    for (int mf = 0; mf < 4; ++mf) {
        int rowbase = (mt0 + mf) * 16 + quad * 4;
        #pragma unroll
        for (int r = 0; r < 4; ++r) {
            int row = rowbase + r;
            int b = row >> 9;
            int hh = hts[row * 2], tt = hts[row * 2 + 1];
            int ent = is_zs ? hh : tt;
            float ev = bf2f(E[(size_t)(b * NEc + ent) * N2 + np]);
            float v = fast_tanh(ev + acc[mf][r] + bias);
            if (is_zs) {
                zs[(size_t)row * Dc + n] = (_Float16)v;
            } else {
                int idx = (((row >> 4) * 24 + (n >> 5)) << 9) +
                          (((((n >> 3) & 3) << 4) + (row & 15)) << 3) + (n & 7);
                zop[idx] = (_Float16)v;
            }
        }
    }
}

// ---------------------------------------------------------------------------
// grouped bilinear: out[row,n] += sum_{x,y} zs[row,gx] zo[row,gy] W[g,x,y,n]
// grid (8 pb, 7 nt, 12 g), 4 waves; wave: M=64, N=16 (zs folded into A in f16)
__global__ __launch_bounds__(256) void k_bilin(const _Float16* __restrict__ zs,
                                               const _Float16* __restrict__ zop,
                                               const _Float16* __restrict__ wbp,
                                               const float* __restrict__ bbi,
                                               float* __restrict__ out) {
    __shared__ _Float16 zlds[256 * 72];
    int tid = threadIdx.x, wave = tid >> 6, lane = tid & 63;
    int quad = lane >> 4, lm = lane & 15;
    int pb = blockIdx.x, nt = blockIdx.y, g = blockIdx.z;
    {
        const half8* src = (const half8*)(zs + ((size_t)(pb * 256 + tid)) * Dc + g * 64);
        half8* dst = (half8*)&zlds[tid * 72];
        #pragma unroll
        for (int c = 0; c < 8; ++c) dst[c] = src[c];   // 64 halves = full group slice
    }
    __syncthreads();
    int mt0 = pb * 16 + wave * 4;
    half8 zofr[4][2];
    #pragma unroll
    for (int mf = 0; mf < 4; ++mf)
        #pragma unroll
        for (int hf = 0; hf < 2; ++hf)
            zofr[mf][hf] = ldh8(zop + (((mt0 + mf) * 24 + g * 2 + hf) << 9) + lane * 8);
    const _Float16* wbase = wbp + ((size_t)(nt * 12 + g) << 16) + lane * 8;
    const _Float16* zrow = &zlds[(wave * 64 + lm) * 72];
    f32x4 acc[4] = {};
    for (int x = 0; x < 64; ++x) {
        half8 b0 = ldh8(wbase + x * 1024);
        half8 b1 = ldh8(wbase + x * 1024 + 512);
        #pragma unroll
        for (int mf = 0; mf < 4; ++mf) {
            _Float16 s = zrow[mf * 16 * 72 + x];
            half8 bc = {s, s, s, s, s, s, s, s};
            acc[mf] = mfma_h(bc * zofr[mf][0], b0, acc[mf]);
            acc[mf] = mfma_h(bc * zofr[mf][1], b1, acc[mf]);
        }
    }
    int n = nt * 16 + lm;
    if (n < NLc) {
        #pragma unroll
        for (int mf = 0; mf < 4; ++mf)
            #pragma unroll
            for (int r = 0; r < 4; ++r) {
                int row = (mt0 + mf) * 16 + quad * 4 + r;
                float v = acc[mf][r];
                if (g == 0) v += bbi[n];
                atomicAdd(out + (size_t)row * NLc + n, v);
            }
    }
}

// ---------------------------------------------------------------------------
extern "C" void kernel_launch(void* const* d_in, const int* in_sizes, int n_in,
                              void* d_out, int out_size, void* d_ws, size_t ws_size,
                              hipStream_t stream) {
    const float* seq  = (const float*)d_in[0];
    const float* att  = (const float*)d_in[1];
    const int*   mpos = (const int*)d_in[2];
    const int*   hts  = (const int*)d_in[3];
    const float* Wh   = (const float*)d_in[4];
    const float* bh   = (const float*)d_in[5];
    const float* Wt   = (const float*)d_in[6];
    const float* bt   = (const float*)d_in[7];
    const float* Wbi  = (const float*)d_in[8];
    const float* bbi  = (const float*)d_in[9];
    float* out = (float*)d_out;

    // Workspace layout
    char* w = (char*)d_ws;
    unsigned short* embs_p = (unsigned short*)(w);                 //   270,336
    unsigned short* eatt_b = (unsigned short*)(w + 270336);        // 4,128,768
    unsigned short* pw_p   = (unsigned short*)(w + 4399104);       // 4,194,304
    unsigned short* seq_p  = (unsigned short*)(w + 8593408);       // 6,291,456
    _Float16*       wbi_p  = (_Float16*)(w + 14884864);            // 11,010,048
    unsigned short* wp1    = (unsigned short*)(w + 25894912);      // 2,359,296
    unsigned short* wp2    = (unsigned short*)(w + 28254208);      // 2,359,296
    unsigned short* E      = (unsigned short*)(w + 30613504);      //   540,672
    unsigned short* rs_p   = (unsigned short*)(w + 31154176);      // 3,145,728
    _Float16*       zs     = (_Float16*)(w + 34299904);            // 3,145,728
    _Float16*       zo_p   = (_Float16*)(w + 37445632);            // 3,145,728
    // total 40,591,360 B

    k_prep <<<PB_TOTAL, 256, 0, stream>>>(seq, att, mpos, Wh, Wt, Wbi,
                                          embs_p, eatt_b, seq_p, wp1, wp2, wbi_p, out);
    k_pairw<<<ROWS, 256, 0, stream>>>(eatt_b, hts, pw_p);
    k_rsE  <<<648, 256, 0, stream>>>(pw_p, seq_p, embs_p, wp1, rs_p, E);
    k_Rz   <<<dim3(32, 24), 256, 0, stream>>>(rs_p, wp2, E, hts, bh, bt, zs, zo_p);
    k_bilin<<<dim3(8, 7, 12), 256, 0, stream>>>(zs, zo_p, wbi_p, bbi, out);
}